// Round 1
// baseline (1546.069 us; speedup 1.0000x reference)
//
#include <hip/hip_runtime.h>

#define IMG_H 800
#define IMG_W 800
#define P_FX 800.0f
#define P_FY 800.0f
#define P_CX 400.0f
#define P_CY 400.0f
#define P_NEAR 0.01f
#define P_FAR 100.0f
#define P_MAXR 16.0f

// One wave (64 lanes) per gaussian; 4 gaussians per 256-thread block.
// All lanes of a wave redundantly compute the per-gaussian projection
// (cheap, avoids LDS+sync), then lanes stride the clamped pixel window.
__global__ __launch_bounds__(256) void splat_kernel(
    const float* __restrict__ positions,
    const float* __restrict__ scales,
    const float* __restrict__ rotations,
    const float* __restrict__ colors,
    const float* __restrict__ opacities,
    const float* __restrict__ phases,
    const float* __restrict__ viewm,
    float* __restrict__ wave_re,
    float* __restrict__ wave_im,
    int pixStride, int chanStride,
    int N)
{
    int g = blockIdx.x * 4 + (threadIdx.x >> 6);
    if (g >= N) return;
    int lane = threadIdx.x & 63;

    // view matrix rows 0..2 (row-major 4x4)
    float V0 = viewm[0],  V1 = viewm[1],  V2 = viewm[2],  V3 = viewm[3];
    float V4 = viewm[4],  V5 = viewm[5],  V6 = viewm[6],  V7 = viewm[7];
    float V8 = viewm[8],  V9 = viewm[9],  V10 = viewm[10], V11 = viewm[11];

    float px_ = positions[g*3+0], py_ = positions[g*3+1], pz_ = positions[g*3+2];
    float x = V0*px_ + V1*py_ + V2*pz_ + V3;
    float y = V4*px_ + V5*py_ + V6*pz_ + V7;
    float z = V8*px_ + V9*py_ + V10*pz_ + V11;
    float depth = -z;

    // quaternion -> rotation matrix (normalized)
    float qw = rotations[g*4+0], qx = rotations[g*4+1], qy = rotations[g*4+2], qz = rotations[g*4+3];
    float qn = sqrtf(qw*qw + qx*qx + qy*qy + qz*qz);
    qn = fmaxf(qn, 1e-12f);
    float qi = 1.0f / qn;
    qw *= qi; qx *= qi; qy *= qi; qz *= qi;
    float R00 = 1.f - 2.f*qy*qy - 2.f*qz*qz, R01 = 2.f*qx*qy - 2.f*qw*qz, R02 = 2.f*qx*qz + 2.f*qw*qy;
    float R10 = 2.f*qx*qy + 2.f*qw*qz, R11 = 1.f - 2.f*qx*qx - 2.f*qz*qz, R12 = 2.f*qy*qz - 2.f*qw*qx;
    float R20 = 2.f*qx*qz - 2.f*qw*qy, R21 = 2.f*qy*qz + 2.f*qw*qx, R22 = 1.f - 2.f*qx*qx - 2.f*qy*qy;

    // R_cam = V[:3,:3] * R
    float C00 = V0*R00 + V1*R10 + V2*R20;
    float C01 = V0*R01 + V1*R11 + V2*R21;
    float C02 = V0*R02 + V1*R12 + V2*R22;
    float C10 = V4*R00 + V5*R10 + V6*R20;
    float C11 = V4*R01 + V5*R11 + V6*R21;
    float C12 = V4*R02 + V5*R12 + V6*R22;
    float C20 = V8*R00 + V9*R10 + V10*R20;
    float C21 = V8*R01 + V9*R11 + V10*R21;
    float C22 = V8*R02 + V9*R12 + V10*R22;

    float sx = scales[g*3+0], sy = scales[g*3+1], sz = scales[g*3+2];
    float A00 = C00*sx, A01 = C01*sy, A02 = C02*sz;
    float A10 = C10*sx, A11 = C11*sy, A12 = C12*sz;
    float A20 = C20*sx, A21 = C21*sy, A22 = C22*sz;

    // cov3d = A * A^T (symmetric)
    float S00 = A00*A00 + A01*A01 + A02*A02;
    float S01 = A00*A10 + A01*A11 + A02*A12;
    float S02 = A00*A20 + A01*A21 + A02*A22;
    float S11 = A10*A10 + A11*A11 + A12*A12;
    float S12 = A10*A20 + A11*A21 + A12*A22;
    float S22 = A20*A20 + A21*A21 + A22*A22;

    float t = z + 1e-8f;
    float sgn = (t > 0.f) ? 1.f : ((t < 0.f) ? -1.f : 0.f);
    float z_safe = fmaxf(fabsf(z), 0.01f) * sgn;
    float z2 = z_safe * z_safe;
    float J00 = P_FX / (-z_safe);
    float J02 = P_FX * x / z2;
    float J11 = P_FY / z_safe;
    float J12 = P_FY * y / z2;

    // M = J * cov3d  (rows 0,1);  cov2d = M * J^T
    float M00 = J00*S00 + J02*S02;
    float M01 = J00*S01 + J02*S12;
    float M02 = J00*S02 + J02*S22;
    float M10 = J11*S01 + J12*S02;
    float M11 = J11*S11 + J12*S12;
    float M12 = J11*S12 + J12*S22;
    float a = M00*J00 + M02*J02;
    float b = M01*J11 + M02*J12;
    float c = M10*J00 + M12*J02;
    float d = M11*J11 + M12*J12;

    float u = P_FX * x / (-z_safe) + P_CX;
    float v = P_FY * (-y) / (-z_safe) + P_CY;

    float trace = a + d;
    float det = fmaxf(a*d - b*c, 1e-6f);
    float disc = fmaxf(trace*trace - 4.f*det, 0.f);
    float max_eig = 0.5f * (trace + sqrtf(disc));
    float radii = fminf(3.f * sqrtf(fmaxf(max_eig, 1e-6f)), P_MAXR);

    bool visible = (depth > P_NEAR) && (depth < P_FAR)
                && (u + radii > 0.f) && (u - radii < (float)IMG_W)
                && (v + radii > 0.f) && (v - radii < (float)IMG_H);
    if (!visible) return;

    float ra = a + 1e-4f, rd = d + 1e-4f;
    float rdet = ra*rd - b*c;
    float ia  = rd / rdet;
    float ibc = -(b + c) / rdet;
    float idd = ra / rdet;

    int x_lo = (int)floorf(u - radii), x_hi = (int)floorf(u + radii);
    int y_lo = (int)floorf(v - radii), y_hi = (int)floorf(v + radii);
    int x0 = max(x_lo, 0), x1 = min(x_hi, IMG_W - 1);
    int y0 = max(y_lo, 0), y1 = min(y_hi, IMG_H - 1);
    if (x1 < x0 || y1 < y0) return;

    float op = opacities[g];
    float ph = phases[g];
    float sp, cp;
    sincosf(ph, &sp, &cp);
    float cr = colors[g*3+0], cg = colors[g*3+1], cb = colors[g*3+2];
    float krc = op*cr*cp, kgc = op*cg*cp, kbc = op*cb*cp;
    float krs = op*cr*sp, kgs = op*cg*sp, kbs = op*cb*sp;

    int nx = x1 - x0 + 1;
    int ny = y1 - y0 + 1;
    int total = nx * ny;
    for (int i = lane; i < total; i += 64) {
        int iy = i / nx;
        int ix = i - iy * nx;
        int pxi = x0 + ix;
        int pyi = y0 + iy;
        float dx = (float)pxi - u;
        float dy = (float)pyi - v;
        float m = ia*dx*dx + ibc*dx*dy + idd*dy*dy;
        float e = expf(-0.5f * m);
        int pix = pyi * IMG_W + pxi;
        float* pr = wave_re + (size_t)pix * pixStride;
        float* pi = wave_im + (size_t)pix * pixStride;
        atomicAdd(pr + 0*chanStride, e * krc);
        atomicAdd(pr + 1*chanStride, e * kgc);
        atomicAdd(pr + 2*chanStride, e * kbc);
        atomicAdd(pi + 0*chanStride, e * krs);
        atomicAdd(pi + 1*chanStride, e * kgs);
        atomicAdd(pi + 2*chanStride, e * kbs);
    }
}

__global__ __launch_bounds__(256) void finalize_kernel(
    const float* __restrict__ wave_re,
    const float* __restrict__ wave_im,
    float* __restrict__ out,
    int pixStride, int chanStride)
{
    int pix = blockIdx.x * blockDim.x + threadIdx.x;
    if (pix >= IMG_H * IMG_W) return;
    #pragma unroll
    for (int ch = 0; ch < 3; ++ch) {
        float re = wave_re[(size_t)pix * pixStride + ch * chanStride];
        float im = wave_im[(size_t)pix * pixStride + ch * chanStride];
        out[ch * (IMG_H * IMG_W) + pix] = re*re + im*im;
    }
}

extern "C" void kernel_launch(void* const* d_in, const int* in_sizes, int n_in,
                              void* d_out, int out_size, void* d_ws, size_t ws_size,
                              hipStream_t stream) {
    const float* positions = (const float*)d_in[0];
    const float* scales    = (const float*)d_in[1];
    const float* rotations = (const float*)d_in[2];
    const float* colors    = (const float*)d_in[3];
    const float* opacities = (const float*)d_in[4];
    const float* phases    = (const float*)d_in[5];
    const float* viewm     = (const float*)d_in[6];
    float* out = (float*)d_out;

    int N = in_sizes[4];  // opacities is (N,)
    const size_t HW = (size_t)IMG_H * IMG_W;
    const size_t need_inter = HW * 6 * sizeof(float);

    int splat_blocks = (N + 3) / 4;
    int fin_blocks = (int)((HW + 255) / 256);

    if (ws_size >= need_inter) {
        // interleaved: per pixel [rR,gR,bR,rI,gI,bI]
        float* ws = (float*)d_ws;
        hipMemsetAsync(ws, 0, need_inter, stream);
        splat_kernel<<<splat_blocks, 256, 0, stream>>>(
            positions, scales, rotations, colors, opacities, phases, viewm,
            ws, ws + 3, 6, 1, N);
        finalize_kernel<<<fin_blocks, 256, 0, stream>>>(ws, ws + 3, out, 6, 1);
    } else {
        // planar fallback: real in d_out (c*HW+pix), imag in ws
        float* im = (float*)d_ws;
        hipMemsetAsync(out, 0, HW * 3 * sizeof(float), stream);
        hipMemsetAsync(im, 0, HW * 3 * sizeof(float), stream);
        splat_kernel<<<splat_blocks, 256, 0, stream>>>(
            positions, scales, rotations, colors, opacities, phases, viewm,
            out, im, 1, (int)HW, N);
        finalize_kernel<<<fin_blocks, 256, 0, stream>>>(out, im, out, 1, (int)HW);
    }
}